// Round 19
// baseline (180.614 us; speedup 1.0000x reference)
//
#include <hip/hip_runtime.h>
#include <hip/hip_bf16.h>
#include <stdint.h>

#define M_DIM 8192
#define N_DIM 4096
#define K_DIM 4096

#define BM 256
#define BN 256
#define BK 64                 // bytes of K per LDS tile = one mfma_i32_16x16x64_i8 K
#define NT (K_DIM / BK)       // 64 K-tiles
#define DEPTH 4               // circular LDS pipeline depth

typedef int v4i __attribute__((ext_vector_type(4)));

#define AS1C(p) ((const __attribute__((address_space(1))) void*)(p))
#define AS3(p)  ((__attribute__((address_space(3))) void*)(p))

// ---------------------------------------------------------------------------
// Pack pass, fully-coalesced form: thread handles ONE int4 (4 ints) -> ONE
// packed dword.  Loads: lane-consecutive int4 (1024 B contiguous per wave
// instruction); stores: lane-consecutive dword (256 B contiguous).  The old
// form loaded 4 x int4 at stride 64 B per instruction (25% line utilization).
// x and w are both int8-range int32; outputs A8 (linear) then B8 (linear).
// ---------------------------------------------------------------------------
__device__ __forceinline__ int pack4(int a, int b, int c, int d) {
  return (a & 0xff) | ((b & 0xff) << 8) | ((c & 0xff) << 16) | (d << 24);
}

__global__ void pack_both_kernel(const int* __restrict__ x, const int* __restrict__ w,
                                 int* __restrict__ A8, int* __restrict__ B8,
                                 int nA4, int nTot4) {
  // nA4 = number of int4-groups in x; nTot4 = in x and w combined.
  const int stride = gridDim.x * blockDim.x;
  int idx = blockIdx.x * blockDim.x + threadIdx.x;
#pragma unroll 4
  for (int i = idx; i < nTot4; i += stride) {
    int4 v;
    if (i < nA4) v = ((const int4*)x)[i];
    else         v = ((const int4*)w)[i - nA4];
    int o = pack4(v.x, v.y, v.z, v.w);
    if (i < nA4) A8[i] = o;
    else         B8[i - nA4] = o;
  }
}

// ---------------------------------------------------------------------------
// FINAL CHAMPION (R15, reproduced R18: 127.4 us GEMM / 50% MfmaUtil /
// 0 conflicts): int8 GEMM, 256x256 tile, 8 waves (2Mx4N, per-wave 128x64),
// BK=64B, mfma_i32_16x16x64_i8, DEPTH=4 LDS ring, counted vmcnt (4/0), ONE
// barrier per K-tile, cross-tile register prefetch, setprio ON (R12: +6%),
// STATIC WAVE ANTI-PHASING (R15: +3%): even waves run reads->MFMA, odd waves
// run MFMA->reads, so the 2 waves per SIMD feed the LDS unit and MFMA pipe
// concurrently instead of alternating.
//
// Rejected by measurement: phase-split lgkm0 (R5 -8%), 2 blocks/CU (R6 -18%),
// m201 dual-barrier (R7 -10%), fat wave 1/SIMD (R9 -12%), static addressing
// (R10 null), B-in-registers (R11 -66%, R16 L2-thrash), setprio removal
// (R12 -6%), 32x32 MFMA (R3=R13, intrinsic 2x LDS conflict: 64B rows give
// rows r,r+2 the same bank base and chunk-XOR has only 4 slots for 16
// aliased rows -- unfixable without padding, which global_load_lds forbids),
// persistence (R17 null).
// ---------------------------------------------------------------------------
__global__ __launch_bounds__(512, 2) void gemm_i8_kernel(
    const char* __restrict__ A8, const char* __restrict__ B8,
    const int* __restrict__ bias, const float* __restrict__ alpha_p,
    const float* __restrict__ beta_p, int* __restrict__ out) {
  __shared__ alignas(16) char lds[DEPTH][BM * BK + BN * BK];  // 4 x 32 KiB

  const int tid  = threadIdx.x;
  const int lane = tid & 63;
  const int wave = tid >> 6;

  // XCD-aware bijective swizzle: 512 blocks, 64 consecutive per XCD.
  const int orig = blockIdx.x;
  const int swz  = (orig & 7) * (512 / 8) + (orig >> 3);
  const int bm   = (swz >> 4) * BM;  // 32 row-tiles
  const int bn   = (swz & 15) * BN;  // 16 col-tiles

  // Staging geometry: per operand tile 16 KB = 2 rounds x 512 thr x 16 B.
  // Pre-swizzled global chunk g = p ^ ((row>>1)&3) (both-sides swizzle).
  int aoff[2], boff[2], ldsoff[2];
#pragma unroll
  for (int i = 0; i < 2; ++i) {
    int linear = i * 8192 + tid * 16;
    int row = linear >> 6;           // 64 B rows
    int p   = (linear >> 4) & 3;
    int g   = p ^ ((row >> 1) & 3);
    ldsoff[i] = i * 8192 + wave * 1024;       // wave-uniform LDS base
    aoff[i] = (bm + row) * K_DIM + g * 16;
    boff[i] = (bn + row) * K_DIM + g * 16;
  }

#define STAGE_A(t)                                                                  \
  do {                                                                              \
    const char* ab_ = A8 + (size_t)(t) * BK;                                        \
    char* base_ = &lds[(t) & (DEPTH - 1)][0];                                       \
    _Pragma("unroll") for (int i_ = 0; i_ < 2; ++i_)                                \
      __builtin_amdgcn_global_load_lds(AS1C(ab_ + aoff[i_]),                        \
                                       AS3(base_ + ldsoff[i_]), 16, 0, 0);          \
  } while (0)

#define STAGE_B(t)                                                                  \
  do {                                                                              \
    const char* bb_ = B8 + (size_t)(t) * BK;                                        \
    char* base_ = &lds[(t) & (DEPTH - 1)][0];                                       \
    _Pragma("unroll") for (int i_ = 0; i_ < 2; ++i_)                                \
      __builtin_amdgcn_global_load_lds(AS1C(bb_ + boff[i_]),                        \
                                       AS3(base_ + 16384 + ldsoff[i_]), 16, 0, 0);  \
  } while (0)

  v4i acc[8][4];
#pragma unroll
  for (int i = 0; i < 8; ++i)
#pragma unroll
    for (int j = 0; j < 4; ++j) acc[i][j] = (v4i){0, 0, 0, 0};

  const int wr = wave >> 2;         // 0..1 (M half: 128 rows)
  const int wc = wave & 3;          // 0..3 (N quarter: 64 cols)
  const int frow = lane & 15;
  const int fchunk = lane >> 4;
  // swizzle XOR depends only on frow (rows differ by multiples of 16) -> lane-const
  const int swzoff = ((fchunk ^ ((frow >> 1) & 3)) << 4);

  // Ping-pong lo-fragment sets (static names, rule #20) + shared afhi.
  v4i bf0[4], aflo0[4], bf1[4], aflo1[4], afhi[4];

#define READ0(S, t)                                                                 \
  do {                                                                              \
    const char* base_ = &lds[(t) & (DEPTH - 1)][0];                                 \
    _Pragma("unroll") for (int nj = 0; nj < 4; ++nj)                                \
      bf##S[nj] = *(const v4i*)(base_ + 16384 + (wc * 64 + nj * 16 + frow) * 64 +   \
                                swzoff);                                            \
    _Pragma("unroll") for (int mi = 0; mi < 4; ++mi)                                \
      aflo##S[mi] = *(const v4i*)(base_ + (wr * 128 + mi * 16 + frow) * 64 +        \
                                  swzoff);                                          \
  } while (0)

#define READ1(t)                                                                    \
  do {                                                                              \
    const char* base_ = &lds[(t) & (DEPTH - 1)][0];                                 \
    _Pragma("unroll") for (int mi = 0; mi < 4; ++mi)                                \
      afhi[mi] = *(const v4i*)(base_ + (wr * 128 + (mi + 4) * 16 + frow) * 64 +     \
                               swzoff);                                             \
  } while (0)

#define MFMA_LO(S)                                                                  \
  do {                                                                              \
    __builtin_amdgcn_s_setprio(1);                                                  \
    _Pragma("unroll") for (int mi = 0; mi < 4; ++mi)                                \
      _Pragma("unroll") for (int nj = 0; nj < 4; ++nj)                              \
        acc[mi][nj] = __builtin_amdgcn_mfma_i32_16x16x64_i8(aflo##S[mi], bf##S[nj], \
                                                            acc[mi][nj], 0, 0, 0); \
    __builtin_amdgcn_s_setprio(0);                                                  \
  } while (0)

#define MFMA_HI(S)                                                                  \
  do {                                                                              \
    __builtin_amdgcn_s_setprio(1);                                                  \
    _Pragma("unroll") for (int mi = 0; mi < 4; ++mi)                                \
      _Pragma("unroll") for (int nj = 0; nj < 4; ++nj)                              \
        acc[mi + 4][nj] = __builtin_amdgcn_mfma_i32_16x16x64_i8(afhi[mi], bf##S[nj],\
                                                                acc[mi + 4][nj],   \
                                                                0, 0, 0);          \
    __builtin_amdgcn_s_setprio(0);                                                  \
  } while (0)

#define EVWAIT(EV)                                                                  \
  do {                                                                              \
    if ((EV) == 4) asm volatile("s_waitcnt vmcnt(4)" ::: "memory");                 \
    if ((EV) == 0) asm volatile("s_waitcnt vmcnt(0)" ::: "memory");                 \
    if ((EV) >= 0) __builtin_amdgcn_s_barrier();                                    \
  } while (0)

// Even group: LDS first, MFMA second.
#define TILE_E(t, C, N, STG, EV)                                                    \
  do {                                                                              \
    if (STG) STAGE_A((t) + 3);                                                      \
    READ1(t);                                                                       \
    MFMA_LO(C);                                                                     \
    if (STG) STAGE_B((t) + 3);                                                      \
    if ((t) + 1 < NT) READ0(N, (t) + 1);                                            \
    MFMA_HI(C);                                                                     \
    EVWAIT(EV);                                                                     \
  } while (0)

// Odd group: MFMA first, LDS second (anti-phase).
#define TILE_O(t, C, N, STG, EV)                                                    \
  do {                                                                              \
    MFMA_LO(C);                                                                     \
    if (STG) STAGE_A((t) + 3);                                                      \
    READ1(t);                                                                       \
    MFMA_HI(C);                                                                     \
    if (STG) STAGE_B((t) + 3);                                                      \
    if ((t) + 1 < NT) READ0(N, (t) + 1);                                            \
    EVWAIT(EV);                                                                     \
  } while (0)

  // Prologue (common): stage tiles 0..2; vmcnt(4) -> tiles 0,1 landed;
  // read tile-0 lo-frags so MFMA_LO(0) is resident for both groups.
  STAGE_A(0); STAGE_B(0);
  STAGE_A(1); STAGE_B(1);
  STAGE_A(2); STAGE_B(2);
  asm volatile("s_waitcnt vmcnt(4)" ::: "memory");
  __builtin_amdgcn_s_barrier();
  READ0(0, 0);

  if ((wave & 4) == 0) {
    for (int t = 0; t < NT - 4; t += 2) {   // t = 0..58: stages 3..62
      TILE_E(t, 0, 1, true, 4);
      TILE_E(t + 1, 1, 0, true, 4);
    }
    TILE_E(NT - 4, 0, 1, true, 4);          // t=60: stages tile 63
    TILE_E(NT - 3, 1, 0, false, 0);         // t=61: vmcnt(0) -> 63 landed
    TILE_E(NT - 2, 0, 1, false, -1);        // t=62: reads tile 63 frags
    TILE_E(NT - 1, 1, 0, false, -1);        // t=63
  } else {
    for (int t = 0; t < NT - 4; t += 2) {
      TILE_O(t, 0, 1, true, 4);
      TILE_O(t + 1, 1, 0, true, 4);
    }
    TILE_O(NT - 4, 0, 1, true, 4);
    TILE_O(NT - 3, 1, 0, false, 0);
    TILE_O(NT - 2, 0, 1, false, -1);
    TILE_O(NT - 1, 1, 0, false, -1);
  }

  // Epilogue: D = rint(alpha*acc + beta*bias[n]).
  // C/D layout (16x16): col = lane&15, row = (lane>>4)*4 + reg.
  const float alpha = *alpha_p;
  const float beta  = *beta_p;
  const int col0 = bn + wc * 64 + frow;
  float bb4[4];
#pragma unroll
  for (int nj = 0; nj < 4; ++nj) bb4[nj] = beta * (float)bias[col0 + nj * 16];

  const int rbase = bm + wr * 128 + (lane >> 4) * 4;
#pragma unroll
  for (int mi = 0; mi < 8; ++mi) {
#pragma unroll
    for (int r = 0; r < 4; ++r) {
      size_t rowoff = (size_t)(rbase + mi * 16 + r) * N_DIM;
#pragma unroll
      for (int nj = 0; nj < 4; ++nj) {
        out[rowoff + col0 + nj * 16] =
            (int)rintf(fmaf(alpha, (float)acc[mi][nj][r], bb4[nj]));
      }
    }
  }
#undef STAGE_A
#undef STAGE_B
#undef READ0
#undef READ1
#undef MFMA_LO
#undef MFMA_HI
#undef EVWAIT
#undef TILE_E
#undef TILE_O
}

// ---------------------------------------------------------------------------
// Safety fallback if ws is too small for the packed operands (slow but right).
// ---------------------------------------------------------------------------
__global__ void naive_kernel(const int* __restrict__ x, const int* __restrict__ w,
                             const int* __restrict__ bias,
                             const float* __restrict__ alpha_p,
                             const float* __restrict__ beta_p,
                             int* __restrict__ out) {
  size_t idx = (size_t)blockIdx.x * 256 + threadIdx.x;
  int m = (int)(idx / N_DIM);
  int n = (int)(idx % N_DIM);
  const int4* xr = (const int4*)(x + (size_t)m * K_DIM);
  const int4* wr = (const int4*)(w + (size_t)n * K_DIM);
  int acc = 0;
  for (int k = 0; k < K_DIM / 4; ++k) {
    int4 a = xr[k];
    int4 b = wr[k];
    acc += a.x * b.x + a.y * b.y + a.z * b.z + a.w * b.w;
  }
  out[idx] = (int)rintf(fmaf(*alpha_p, (float)acc, (*beta_p) * (float)bias[n]));
}

extern "C" void kernel_launch(void* const* d_in, const int* in_sizes, int n_in,
                              void* d_out, int out_size, void* d_ws, size_t ws_size,
                              hipStream_t stream) {
  const int*   x     = (const int*)d_in[0];
  const int*   w     = (const int*)d_in[1];
  const int*   bias  = (const int*)d_in[2];
  const float* alpha = (const float*)d_in[3];
  const float* beta  = (const float*)d_in[4];
  int* out = (int*)d_out;

  const size_t a8_bytes = (size_t)M_DIM * K_DIM;  // 32 MiB
  const size_t b8_bytes = (size_t)N_DIM * K_DIM;  // 16 MiB

  if (ws_size >= a8_bytes + b8_bytes) {
    char* A8 = (char*)d_ws;
    char* B8 = A8 + a8_bytes;
    const int nA4   = (int)(a8_bytes / 4);               // int4-groups in x
    const int nTot4 = (int)((a8_bytes + b8_bytes) / 4);  // + groups in w
    pack_both_kernel<<<2048, 256, 0, stream>>>(x, w, (int*)A8, (int*)B8, nA4, nTot4);
    const int nblk = (M_DIM / BM) * (N_DIM / BN);  // 32*16 = 512
    gemm_i8_kernel<<<nblk, 512, 0, stream>>>(A8, B8, bias, alpha, beta, out);
  } else {
    naive_kernel<<<(M_DIM * (size_t)N_DIM) / 256, 256, 0, stream>>>(x, w, bias, alpha, beta, out);
  }
}